// Round 2
// baseline (801.258 us; speedup 1.0000x reference)
//
#include <hip/hip_runtime.h>
#include <cstdint>

typedef __attribute__((ext_vector_type(8))) short s8v;   // 8 x bf16 (as i16)
typedef __attribute__((ext_vector_type(4))) float f4v;   // MFMA accumulator

__device__ __forceinline__ unsigned short bf16_rne(float f) {
    unsigned u = __float_as_uint(f);
    u += 0x7FFFu + ((u >> 16) & 1u);
    return (unsigned short)(u >> 16);
}
__device__ __forceinline__ float bf16f(unsigned short h) {
    return __uint_as_float(((unsigned)h) << 16);
}

// ---------------- prep: conv_w [o][c][9] fp32 -> A'hi/A'lo [r][o][c] bf16 ----------------
__global__ __launch_bounds__(256) void prep_w(const float* __restrict__ w,
                                              unsigned short* __restrict__ Ahi,
                                              unsigned short* __restrict__ Alo) {
    size_t idx = (size_t)blockIdx.x * 256 + threadIdx.x;  // = o*2048 + c
    const float* src = w + idx * 9;
    float v[9];
#pragma unroll
    for (int r = 0; r < 9; ++r) v[r] = src[r];
#pragma unroll
    for (int r = 0; r < 9; ++r) {
        unsigned short hi = bf16_rne(v[r]);
        unsigned short lo = bf16_rne(v[r] - bf16f(hi));
        size_t a = (size_t)r * (2048u * 2048u) + idx;
        Ahi[a] = hi;
        Alo[a] = lo;
    }
}

// ---------------- prep: x [c][28*28] fp32 -> X'hi/X'lo [q=30x30 padded pixel][c] bf16 ----
__global__ __launch_bounds__(256) void prep_x(const float* __restrict__ x,
                                              unsigned short* __restrict__ Xhi,
                                              unsigned short* __restrict__ Xlo) {
    __shared__ float t[64][65];
    int c0 = blockIdx.x * 64, p0 = blockIdx.y * 64;
    int l = threadIdx.x & 63, g = threadIdx.x >> 6;
#pragma unroll
    for (int j = 0; j < 16; ++j) {
        int cl = j * 4 + g;
        int p = p0 + l;
        t[cl][l] = (p < 784) ? x[(size_t)(c0 + cl) * 784 + p] : 0.f;
    }
    __syncthreads();
#pragma unroll
    for (int j = 0; j < 16; ++j) {
        int pl = j * 4 + g;
        int p = p0 + pl;
        if (p < 784) {
            int q = (p / 28 + 1) * 30 + (p % 28) + 1;  // interior of 30x30 zero-padded image
            float v = t[l][pl];
            unsigned short hi = bf16_rne(v);
            unsigned short lo = bf16_rne(v - bf16f(hi));
            Xhi[(size_t)q * 2048 + c0 + l] = hi;
            Xlo[(size_t)q * 2048 + c0 + l] = lo;
        }
    }
}

// ---------------- conv as implicit GEMM, bf16x3, r-split, global_load_lds staging --------
#define AHI_OFF 0
#define ALO_OFF 16384
#define BHI_OFF 32768
#define BLO_OFF 39936
#define LDS_BYTES 47104

__global__ __launch_bounds__(256, 2) void conv_gemm(const char* __restrict__ wsb,
                                                    uint32_t offAhi, uint32_t offAlo,
                                                    uint32_t offXhi, uint32_t offXlo,
                                                    float* __restrict__ hbuf) {
    __shared__ char smem[LDS_BYTES];
    int tid = threadIdx.x;
    int lane = tid & 63, wave = tid >> 6;
    int bm0 = blockIdx.x * 256, bn0 = blockIdx.y * 112, r = blockIdx.z;
    int dh = r / 3 - 1, dw2 = r % 3 - 1;
    int offr = dh * 30 + dw2;

    // 48 staging descriptors (46 real + 2 benign dups), 12 per wave.
    uint32_t doff[12];
    uint32_t dlds[12];
#pragma unroll
    for (int j = 0; j < 12; ++j) {
        int i = wave + 4 * j;
        if (i >= 46) i -= 2;
        uint32_t gbyte, lofs;
        if (i < 32) {  // A tiles: 16 rows x 64B per instr
            int jj = i & 15;
            int row = jj * 16 + (lane >> 2);
            int pos = lane & 3;
            int gblk = pos ^ ((row >> 1) & 3);  // XOR swizzle @16B granularity
            uint32_t elem = ((uint32_t)((r << 11) + bm0 + row) << 11) + gblk * 8;
            gbyte = ((i < 16) ? offAhi : offAlo) + elem * 2;
            lofs = ((i < 16) ? AHI_OFF : ALO_OFF) + jj * 1024;
        } else {  // B tiles from padded image
            int jj = (i - 32) % 7;
            bool hi = i < 39;
            int prow = jj * 16 + (lane >> 2);
            int pos = lane & 3;
            int p = bn0 + prow;
            int q = (p / 28 + 1) * 30 + (p % 28) + 1 + offr;  // zero border handles OOB
            int gblk = pos ^ ((prow >> 1) & 3);
            uint32_t elem = ((uint32_t)q << 11) + gblk * 8;
            gbyte = (hi ? offXhi : offXlo) + elem * 2;
            lofs = (hi ? BHI_OFF : BLO_OFF) + jj * 1024;
        }
        doff[j] = gbyte;
        dlds[j] = lofs;
    }

    int m = lane & 15, qd = lane >> 4;
    int sw = (m >> 1) & 3;
    uint32_t apos = (uint32_t)(wave * 64 + m) * 64 + (uint32_t)((qd ^ sw) * 16);
    uint32_t bpos = (uint32_t)m * 64 + (uint32_t)((qd ^ sw) * 16);

    f4v acc[4][7];
#pragma unroll
    for (int a = 0; a < 4; ++a)
#pragma unroll
        for (int b = 0; b < 7; ++b) acc[a][b] = f4v{0.f, 0.f, 0.f, 0.f};

    for (int step = 0; step < 64; ++step) {
#pragma unroll
        for (int j = 0; j < 12; ++j) {
            __builtin_amdgcn_global_load_lds(
                (const __attribute__((address_space(1))) void*)(wsb + doff[j]),
                (__attribute__((address_space(3))) void*)(smem + dlds[j]), 16, 0, 0);
            doff[j] += 64;  // advance 32 bf16 along c
        }
        __syncthreads();

        s8v ah[4], al[4];
#pragma unroll
        for (int mt = 0; mt < 4; ++mt) {
            ah[mt] = *(const s8v*)(smem + AHI_OFF + apos + mt * 1024);
            al[mt] = *(const s8v*)(smem + ALO_OFF + apos + mt * 1024);
        }
#pragma unroll
        for (int nt = 0; nt < 7; ++nt) {
            s8v bh = *(const s8v*)(smem + BHI_OFF + bpos + nt * 1024);
            s8v bl = *(const s8v*)(smem + BLO_OFF + bpos + nt * 1024);
#pragma unroll
            for (int mt = 0; mt < 4; ++mt) {
                acc[mt][nt] = __builtin_amdgcn_mfma_f32_16x16x32_bf16(ah[mt], bh, acc[mt][nt], 0, 0, 0);
                acc[mt][nt] = __builtin_amdgcn_mfma_f32_16x16x32_bf16(ah[mt], bl, acc[mt][nt], 0, 0, 0);
                acc[mt][nt] = __builtin_amdgcn_mfma_f32_16x16x32_bf16(al[mt], bh, acc[mt][nt], 0, 0, 0);
            }
        }
        __syncthreads();
    }

    // epilogue: C row = qd*4+reg (o), col = lane&15 (p); accumulate 9 r-partials
#pragma unroll
    for (int mt = 0; mt < 4; ++mt) {
        int o = bm0 + wave * 64 + mt * 16 + qd * 4;
#pragma unroll
        for (int nt = 0; nt < 7; ++nt) {
            int p = bn0 + nt * 16 + m;
            float* hp = hbuf + (size_t)p * 2048 + o;
            f4v v = acc[mt][nt];
            atomicAdd(hp + 0, v.x);
            atomicAdd(hp + 1, v.y);
            atomicAdd(hp + 2, v.z);
            atomicAdd(hp + 3, v.w);
        }
    }
}

// ---------------- heads: bias+ReLU, 45-way dot, sigmoid, reference-exact gather/scatter --
// valid ⟺ hh >= HMIN[a] && ww >= WMIN[a]  (y2<28/x2<28 are vacuous after /448 normalize)
__constant__ int HMIN_d[9] = {3, 2, 1, 6, 4, 3, 11, 8, 6};
__constant__ int WMIN_d[9] = {1, 2, 3, 3, 4, 6, 6, 8, 11};

__global__ __launch_bounds__(256) void heads(const float* __restrict__ hbuf,
                                             const float* __restrict__ conv_b,
                                             const float* __restrict__ reg_w,
                                             const float* __restrict__ reg_b,
                                             const float* __restrict__ cls_w,
                                             const float* __restrict__ cls_b,
                                             float* __restrict__ out) {
    int lane = threadIdx.x & 63, wave = threadIdx.x >> 6;
    int p = blockIdx.x * 4 + wave;  // source pixel p' ; 196 blocks x 4 pixels
    float s[45];
#pragma unroll
    for (int o = 0; o < 45; ++o) s[o] = 0.f;

    const float4* hp = (const float4*)(hbuf + (size_t)p * 2048);
    const float4* bp = (const float4*)conv_b;
#pragma unroll
    for (int it = 0; it < 8; ++it) {
        int ci = it * 64 + lane;
        float4 hv = hp[ci];
        float4 bb = bp[ci];
        hv.x = fmaxf(hv.x + bb.x, 0.f);
        hv.y = fmaxf(hv.y + bb.y, 0.f);
        hv.z = fmaxf(hv.z + bb.z, 0.f);
        hv.w = fmaxf(hv.w + bb.w, 0.f);
#pragma unroll
        for (int o = 0; o < 36; ++o) {
            float4 w = ((const float4*)(reg_w + (size_t)o * 2048))[ci];
            s[o] += hv.x * w.x + hv.y * w.y + hv.z * w.z + hv.w * w.w;
        }
#pragma unroll
        for (int a = 0; a < 9; ++a) {
            float4 w = ((const float4*)(cls_w + (size_t)a * 2048))[ci];
            s[36 + a] += hv.x * w.x + hv.y * w.y + hv.z * w.z + hv.w * w.w;
        }
    }

    __shared__ float tot[4][45];
#pragma unroll
    for (int o = 0; o < 45; ++o) {
        float v = s[o];
#pragma unroll
        for (int d = 1; d < 64; d <<= 1) v += __shfl_xor(v, d, 64);
        if (lane == 0) tot[wave][o] = v;
    }
    __syncthreads();

    // Reference view-chain replication:
    //   valid set enumerated over n = pix*9 + a  (geometry decomposition)
    //   data gathered at row n from channel a' = n//784, pixel p' = n%784
    // This wave owns source pixel p'. The n's sourcing it are n = a'*784 + p', a' = 0..8.
    if (lane < 9) {
        int ap = lane;                 // a' : cls channel; reg channels q*9+a'
        int n = ap * 784 + p;
        int pix = n / 9, a2 = n % 9;   // geometry pixel/anchor deciding validity & rank
        int hh = pix / 28, ww = pix % 28;
        if (hh >= HMIN_d[a2] && ww >= WMIN_d[a2]) {
            // rank(n) in lex-(pix, a) order over the valid set
            int row = 0;
#pragma unroll
            for (int a3 = 0; a3 < 9; ++a3) {
                int hm = HMIN_d[a3], wm = WMIN_d[a3];
                int full = hh - hm; if (full < 0) full = 0;
                row += full * (28 - wm);                       // full rows before hh
                if (hh >= hm) { int part = ww - wm; if (part < 0) part = 0; row += part; }
                if (a3 < a2 && hh >= hm && ww >= wm) row += 1; // anchors before a2 at pix
            }
            float cl = tot[wave][36 + ap] + cls_b[ap];
            float keep = (1.f / (1.f + expf(-cl)) > 0.9f) ? 1.f : 0.f;
#pragma unroll
            for (int q = 0; q < 4; ++q) {
                float rl = tot[wave][q * 9 + ap] + reg_b[q * 9 + ap];
                out[row * 4 + q] = keep / (1.f + expf(-rl));
            }
        }
    }
}

extern "C" void kernel_launch(void* const* d_in, const int* in_sizes, int n_in,
                              void* d_out, int out_size, void* d_ws, size_t ws_size,
                              hipStream_t stream) {
    const float* x = (const float*)d_in[0];
    const float* conv_w = (const float*)d_in[1];
    const float* conv_b = (const float*)d_in[2];
    const float* reg_w = (const float*)d_in[3];
    const float* reg_b = (const float*)d_in[4];
    const float* cls_w = (const float*)d_in[5];
    const float* cls_b = (const float*)d_in[6];
    float* out = (float*)d_out;
    char* ws = (char*)d_ws;

    // workspace layout (bytes)
    const size_t o_h = 0;            // fp32 conv accumulator [784][2048]  : 6,422,528
    const size_t o_Xhi = 6422528;    // bf16 [900][2048]                    : 3,686,400
    const size_t o_Xlo = 10108928;   // bf16 [900][2048]                    : 3,686,400
    const size_t o_Ahi = 13795328;   // bf16 [9][2048][2048]                : 75,497,472
    const size_t o_Alo = 89292800;   // bf16 [9][2048][2048]                : 75,497,472

    hipMemsetAsync(ws + o_h, 0, 6422528, stream);
    hipMemsetAsync(ws + o_Xhi, 0, 7372800, stream);  // zero borders of both X planes

    prep_x<<<dim3(32, 13), 256, 0, stream>>>(x, (unsigned short*)(ws + o_Xhi),
                                             (unsigned short*)(ws + o_Xlo));
    prep_w<<<16384, 256, 0, stream>>>(conv_w, (unsigned short*)(ws + o_Ahi),
                                      (unsigned short*)(ws + o_Alo));
    conv_gemm<<<dim3(8, 7, 9), 256, 0, stream>>>(ws, (uint32_t)o_Ahi, (uint32_t)o_Alo,
                                                 (uint32_t)o_Xhi, (uint32_t)o_Xlo,
                                                 (float*)(ws + o_h));
    heads<<<196, 256, 0, stream>>>((const float*)(ws + o_h), conv_b, reg_w, reg_b,
                                   cls_w, cls_b, out);
}

// Round 3
// 745.351 us; speedup vs baseline: 1.0750x; 1.0750x over previous
//
#include <hip/hip_runtime.h>
#include <cstdint>

typedef __attribute__((ext_vector_type(8))) short s8v;   // 8 x bf16 (as i16)
typedef __attribute__((ext_vector_type(4))) float f4v;   // MFMA accumulator

__device__ __forceinline__ unsigned short bf16_rne(float f) {
    unsigned u = __float_as_uint(f);
    u += 0x7FFFu + ((u >> 16) & 1u);
    return (unsigned short)(u >> 16);
}
__device__ __forceinline__ float bf16f(unsigned short h) {
    return __uint_as_float(((unsigned)h) << 16);
}
// two fp32 -> packed bf16-hi dword + packed bf16-lo dword (RNE both)
__device__ __forceinline__ void cvt2(float a, float b, unsigned& hiw, unsigned& low) {
    unsigned ua = __float_as_uint(a), ub = __float_as_uint(b);
    unsigned ha = ua + 0x7FFFu + ((ua >> 16) & 1u);
    unsigned hb = ub + 0x7FFFu + ((ub >> 16) & 1u);
    hiw = (ha >> 16) | (hb & 0xFFFF0000u);
    float ra = a - __uint_as_float(ha & 0xFFFF0000u);
    float rb = b - __uint_as_float(hb & 0xFFFF0000u);
    unsigned la = __float_as_uint(ra), lb = __float_as_uint(rb);
    la += 0x7FFFu + ((la >> 16) & 1u);
    lb += 0x7FFFu + ((lb >> 16) & 1u);
    low = (la >> 16) | (lb & 0xFFFF0000u);
}

// ---------------- build im2col B: x [c][784] fp32 -> Bhi/Blo [p][k=c*9+r] bf16 -----------
// Each thread owns (pixel p, c-pair) -> 18 consecutive k -> 9 aligned dword stores/plane.
__global__ __launch_bounds__(256) void build_B(const float* __restrict__ x,
                                               unsigned* __restrict__ Bhi,
                                               unsigned* __restrict__ Blo) {
    int p = blockIdx.x >> 2;
    int c0 = (((blockIdx.x & 3) << 8) + threadIdx.x) << 1;  // even c in [0,2046]
    int h = p / 28, w = p % 28;
    unsigned short hs[18], ls[18];
#pragma unroll
    for (int j = 0; j < 2; ++j) {
        const float* xc = x + (size_t)(c0 + j) * 784;
#pragma unroll
        for (int r = 0; r < 9; ++r) {
            int h2 = h + r / 3 - 1, w2 = w + r % 3 - 1;
            bool ok = (h2 >= 0) & (h2 < 28) & (w2 >= 0) & (w2 < 28);
            float v = ok ? xc[h2 * 28 + w2] : 0.f;
            unsigned short hh = bf16_rne(v);
            hs[j * 9 + r] = hh;
            ls[j * 9 + r] = bf16_rne(v - bf16f(hh));
        }
    }
    size_t base = (size_t)p * 9216 + (size_t)(c0 * 9) / 2;  // dword index
#pragma unroll
    for (int d = 0; d < 9; ++d) {
        Bhi[base + d] = (unsigned)hs[2 * d] | ((unsigned)hs[2 * d + 1] << 16);
        Blo[base + d] = (unsigned)ls[2 * d] | ((unsigned)ls[2 * d + 1] << 16);
    }
}

// ---------------- conv as implicit GEMM over k=c*9+r; A = conv_w direct (in-loop split) --
// z splits K into 9 chunks of 2048; each block plain-stores its fp32 partial (no atomics).
#define AHI_OFF 0
#define ALO_OFF 16384
#define BHI_OFF 32768
#define BLO_OFF 39936
#define LDS_BYTES 47104

__global__ __launch_bounds__(256, 2) void conv_gemm(const float* __restrict__ cw,
                                                    const char* __restrict__ wsb,
                                                    uint32_t offBhi, uint32_t offBlo,
                                                    float* __restrict__ part) {
    __shared__ char smem[LDS_BYTES];
    int tid = threadIdx.x;
    int lane = tid & 63, wave = tid >> 6;
    int bm0 = blockIdx.x * 256, bn0 = blockIdx.y * 112, z = blockIdx.z;

    // B staging: 14 real glds descriptors (7 hi-tiles + 7 lo-tiles) + 2 benign dups.
    uint32_t doff[4], dlds[4];
#pragma unroll
    for (int j = 0; j < 4; ++j) {
        int i = j * 4 + wave;           // 0..15
        if (i >= 14) i -= 2;            // dup of lo tiles 5,6 (same src+dst: benign)
        bool hiP = i < 7;
        int jj = hiP ? i : i - 7;
        int prow = jj * 16 + (lane >> 2);
        int pos = lane & 3;
        int gblk = pos ^ ((prow >> 1) & 3);            // XOR swizzle @16B blocks
        uint32_t elem = (uint32_t)(bn0 + prow) * 18432 + (uint32_t)z * 2048 + gblk * 8;
        doff[j] = (hiP ? offBhi : offBlo) + elem * 2;
        dlds[j] = (hiP ? BHI_OFF : BLO_OFF) + jj * 1024;
    }

    int m = lane & 15, qd = lane >> 4;
    int sw = (m >> 1) & 3;
    uint32_t apos = (uint32_t)(wave * 64 + m) * 64 + (uint32_t)((qd ^ sw) * 16);
    uint32_t bpos = (uint32_t)m * 64 + (uint32_t)((qd ^ sw) * 16);
    int swt = (tid >> 1) & 3;                          // writer-row swizzle (row = tid)

    f4v acc[4][7];
#pragma unroll
    for (int a = 0; a < 4; ++a)
#pragma unroll
        for (int b = 0; b < 7; ++b) acc[a][b] = f4v{0.f, 0.f, 0.f, 0.f};

    // A: row o = bm0 + tid of conv_w, contiguous fp32 along k. Prefetch step 0.
    const float4* ap = (const float4*)(cw + (size_t)(bm0 + tid) * 18432 + (size_t)z * 2048);
    float4 ar[8];
#pragma unroll
    for (int j = 0; j < 8; ++j) ar[j] = ap[j];
    ap += 8;

    for (int step = 0; step < 64; ++step) {
        // B: async global->LDS
#pragma unroll
        for (int j = 0; j < 4; ++j) {
            __builtin_amdgcn_global_load_lds(
                (const __attribute__((address_space(1))) void*)(wsb + doff[j]),
                (__attribute__((address_space(3))) void*)(smem + dlds[j]), 16, 0, 0);
            doff[j] += 64;  // 32 k * 2B
        }
        // A: split fp32 -> bf16 hi/lo, pack, LDS write (row tid, swizzled 16B blocks)
        unsigned hw[16], lw[16];
#pragma unroll
        for (int j = 0; j < 8; ++j) {
            cvt2(ar[j].x, ar[j].y, hw[2 * j], lw[2 * j]);
            cvt2(ar[j].z, ar[j].w, hw[2 * j + 1], lw[2 * j + 1]);
        }
#pragma unroll
        for (int b = 0; b < 4; ++b) {
            uint32_t col = (uint32_t)((b ^ swt) * 16);
            *(uint4*)(smem + AHI_OFF + tid * 64 + col) =
                uint4{hw[4 * b], hw[4 * b + 1], hw[4 * b + 2], hw[4 * b + 3]};
            *(uint4*)(smem + ALO_OFF + tid * 64 + col) =
                uint4{lw[4 * b], lw[4 * b + 1], lw[4 * b + 2], lw[4 * b + 3]};
        }
        __syncthreads();

        if (step < 63) {  // VGPR prefetch of next A chunk, overlapped with compute
#pragma unroll
            for (int j = 0; j < 8; ++j) ar[j] = ap[j];
            ap += 8;
        }

        s8v ah[4], al[4];
#pragma unroll
        for (int mt = 0; mt < 4; ++mt) {
            ah[mt] = *(const s8v*)(smem + AHI_OFF + apos + mt * 1024);
            al[mt] = *(const s8v*)(smem + ALO_OFF + apos + mt * 1024);
        }
#pragma unroll
        for (int nt = 0; nt < 7; ++nt) {
            s8v bh = *(const s8v*)(smem + BHI_OFF + bpos + nt * 1024);
            s8v bl = *(const s8v*)(smem + BLO_OFF + bpos + nt * 1024);
#pragma unroll
            for (int mt = 0; mt < 4; ++mt) {
                acc[mt][nt] = __builtin_amdgcn_mfma_f32_16x16x32_bf16(ah[mt], bh, acc[mt][nt], 0, 0, 0);
                acc[mt][nt] = __builtin_amdgcn_mfma_f32_16x16x32_bf16(ah[mt], bl, acc[mt][nt], 0, 0, 0);
                acc[mt][nt] = __builtin_amdgcn_mfma_f32_16x16x32_bf16(al[mt], bh, acc[mt][nt], 0, 0, 0);
            }
        }
        __syncthreads();
    }

    // epilogue: C row(o) = qd*4+reg, col(p) = m; f4v spans 4 consecutive o -> one 16B store
    float* pz = part + (size_t)z * 1605632;  // 784*2048
#pragma unroll
    for (int mt = 0; mt < 4; ++mt) {
        int o = bm0 + wave * 64 + mt * 16 + qd * 4;
#pragma unroll
        for (int nt = 0; nt < 7; ++nt) {
            int p = bn0 + nt * 16 + m;
            *(float4*)(pz + (size_t)p * 2048 + o) =
                float4{acc[mt][nt].x, acc[mt][nt].y, acc[mt][nt].z, acc[mt][nt].w};
        }
    }
}

// ---------------- heads: 9-partial reduce + bias+ReLU, 45-way dot, sigmoid, scatter -----
// valid <=> hh >= HMIN[a] && ww >= WMIN[a]  (y2<28/x2<28 vacuous after /448 normalize)
__constant__ int HMIN_d[9] = {3, 2, 1, 6, 4, 3, 11, 8, 6};
__constant__ int WMIN_d[9] = {1, 2, 3, 3, 4, 6, 6, 8, 11};

__global__ __launch_bounds__(256) void heads(const float* __restrict__ part,
                                             const float* __restrict__ conv_b,
                                             const float* __restrict__ reg_w,
                                             const float* __restrict__ reg_b,
                                             const float* __restrict__ cls_w,
                                             const float* __restrict__ cls_b,
                                             float* __restrict__ out) {
    int lane = threadIdx.x & 63, wave = threadIdx.x >> 6;
    int p = blockIdx.x * 4 + wave;  // source pixel p'; 196 blocks x 4 pixels
    float s[45];
#pragma unroll
    for (int o = 0; o < 45; ++o) s[o] = 0.f;

    const float4* bp = (const float4*)conv_b;
#pragma unroll
    for (int it = 0; it < 8; ++it) {
        int ci = it * 64 + lane;
        float4 hv = bp[ci];
#pragma unroll
        for (int z = 0; z < 9; ++z) {
            float4 pv = ((const float4*)(part + (size_t)z * 1605632 + (size_t)p * 2048))[ci];
            hv.x += pv.x; hv.y += pv.y; hv.z += pv.z; hv.w += pv.w;
        }
        hv.x = fmaxf(hv.x, 0.f);
        hv.y = fmaxf(hv.y, 0.f);
        hv.z = fmaxf(hv.z, 0.f);
        hv.w = fmaxf(hv.w, 0.f);
#pragma unroll
        for (int o = 0; o < 36; ++o) {
            float4 w = ((const float4*)(reg_w + (size_t)o * 2048))[ci];
            s[o] += hv.x * w.x + hv.y * w.y + hv.z * w.z + hv.w * w.w;
        }
#pragma unroll
        for (int a = 0; a < 9; ++a) {
            float4 w = ((const float4*)(cls_w + (size_t)a * 2048))[ci];
            s[36 + a] += hv.x * w.x + hv.y * w.y + hv.z * w.z + hv.w * w.w;
        }
    }

    __shared__ float tot[4][45];
#pragma unroll
    for (int o = 0; o < 45; ++o) {
        float v = s[o];
#pragma unroll
        for (int d = 1; d < 64; d <<= 1) v += __shfl_xor(v, d, 64);
        if (lane == 0) tot[wave][o] = v;
    }
    __syncthreads();

    // Reference view-chain: valid set over n = pix*9 + a (geometry); data at row n from
    // channel a' = n//784, pixel p' = n%784. This wave owns p'; n = a'*784 + p'.
    if (lane < 9) {
        int ap = lane;
        int n = ap * 784 + p;
        int pix = n / 9, a2 = n % 9;
        int hh = pix / 28, ww = pix % 28;
        if (hh >= HMIN_d[a2] && ww >= WMIN_d[a2]) {
            int row = 0;
#pragma unroll
            for (int a3 = 0; a3 < 9; ++a3) {
                int hm = HMIN_d[a3], wm = WMIN_d[a3];
                int full = hh - hm; if (full < 0) full = 0;
                row += full * (28 - wm);
                if (hh >= hm) { int prt = ww - wm; if (prt < 0) prt = 0; row += prt; }
                if (a3 < a2 && hh >= hm && ww >= wm) row += 1;
            }
            float cl = tot[wave][36 + ap] + cls_b[ap];
            float keep = (1.f / (1.f + expf(-cl)) > 0.9f) ? 1.f : 0.f;
#pragma unroll
            for (int q = 0; q < 4; ++q) {
                float rl = tot[wave][q * 9 + ap] + reg_b[q * 9 + ap];
                out[row * 4 + q] = keep / (1.f + expf(-rl));
            }
        }
    }
}

extern "C" void kernel_launch(void* const* d_in, const int* in_sizes, int n_in,
                              void* d_out, int out_size, void* d_ws, size_t ws_size,
                              hipStream_t stream) {
    const float* x = (const float*)d_in[0];
    const float* conv_w = (const float*)d_in[1];
    const float* conv_b = (const float*)d_in[2];
    const float* reg_w = (const float*)d_in[3];
    const float* reg_b = (const float*)d_in[4];
    const float* cls_w = (const float*)d_in[5];
    const float* cls_b = (const float*)d_in[6];
    float* out = (float*)d_out;
    char* ws = (char*)d_ws;

    // workspace layout (bytes) — total 115,605,504 (< proven 165 MB)
    const size_t o_part = 0;          // fp32 partials [9][784][2048] : 57,802,752
    const size_t o_Bhi = 57802752;    // bf16 [784][18432]            : 28,901,376
    const size_t o_Blo = 86704128;    // bf16 [784][18432]            : 28,901,376

    build_B<<<3136, 256, 0, stream>>>(x, (unsigned*)(ws + o_Bhi), (unsigned*)(ws + o_Blo));
    conv_gemm<<<dim3(8, 7, 9), 256, 0, stream>>>(conv_w, ws, (uint32_t)o_Bhi,
                                                 (uint32_t)o_Blo, (float*)(ws + o_part));
    heads<<<196, 256, 0, stream>>>((const float*)(ws + o_part), conv_b, reg_w, reg_b,
                                   cls_w, cls_b, out);
}